// Round 6
// baseline (252.222 us; speedup 1.0000x reference)
//
#include <hip/hip_runtime.h>
#include <hip/hip_bf16.h>

// SE3StructEncoder: sparse edge-MLP graph network. B=2, L=512, H=128, 3 layers.
// Round 6: node/input kernels were L2-latency bound (VALUBusy 7%, 2 scalar
// strided loads per c-iter). Prep kernel transposes node-path weights to [k][c]
// fp32 so each thread streams a private contiguous row as float4 (unroll 8).
// Edge kernel (bf16 MFMA) unchanged from round 5.

#define Hc 128
#define Lc 512
#define ROWS 1024     // B*L

typedef __bf16 bf16x8 __attribute__((ext_vector_type(8)));
typedef float  f32x4  __attribute__((ext_vector_type(4)));

__device__ __forceinline__ float silu(float x) {
    return x / (1.f + __expf(-x));
}

// ---------------- edge-list build: one wave per (b,i) row ----------------
__global__ __launch_bounds__(64) void build_edges(
    const float* __restrict__ contacts,
    unsigned short* __restrict__ elist, int* __restrict__ ecnt) {
    int r = blockIdx.x;
    int lane = threadIdx.x;
    const float* row = contacts + (size_t)r * Lc;
    int cnt = 0;
    for (int base = 0; base < Lc; base += 64) {
        float v = row[base + lane];
        unsigned long long mask = __ballot(v > 0.f);
        if (v > 0.f) {
            int pos = cnt + __popcll(mask & ((1ull << lane) - 1ull));
            elist[r * Lc + pos] = (unsigned short)(base + lane);
        }
        cnt += __popcll(mask);
    }
    if (lane == 0) ecnt[r] = cnt;
}

// ---------- w2 -> bf16 transposed [layer][col][k] (one-time per launch) ----------
__global__ __launch_bounds__(128) void prep_w2t(
    const float* __restrict__ e_w2, __bf16* __restrict__ w2t) {
    int lc = blockIdx.x;            // layer*128 + col
    int l  = lc >> 7, col = lc & 127;
    int k  = threadIdx.x;
    w2t[(size_t)lc * Hc + k] =
        (__bf16)e_w2[(size_t)l * Hc * Hc + (size_t)k * Hc + col];
}

// ---- node-path weights -> fp32 transposed [k][c] (one-time per launch) ----
// w1nt[l][k][c] = n_w1[l][c][k]  (c: 0..255, h-part then m-part)
// w2nt[l][k][c] = n_w2[l][c][k]  (c: 0..127)
// w1et[l][k][c] = e_w1[l][c][k]  (c: 0..255, hi-part then hj-part)
// in_wt[k][c]   = in_w[c][k]     (c: 0..31)
__global__ __launch_bounds__(256) void prep_node_t(
    const float* __restrict__ n_w1, const float* __restrict__ n_w2,
    const float* __restrict__ e_w1, const float* __restrict__ in_w,
    float* __restrict__ w1nt, float* __restrict__ w2nt,
    float* __restrict__ w1et, float* __restrict__ in_wt) {
    int idx = blockIdx.x * 256 + threadIdx.x;   // 976*256 = 249856
    if (idx < 245760) {
        int layer = idx / 81920, r = idx % 81920;
        if (r < 32768) {
            int k = r >> 8, c = r & 255;
            w1nt[layer * 32768 + r] = n_w1[(size_t)layer * 32768 + c * Hc + k];
        } else if (r < 49152) {
            int q = r - 32768;
            int k = q >> 7, c = q & 127;
            w2nt[layer * 16384 + q] = n_w2[(size_t)layer * 16384 + c * Hc + k];
        } else {
            int q = r - 49152;
            int k = q >> 8, c = q & 255;
            w1et[layer * 32768 + q] = e_w1[(size_t)layer * 258 * Hc + c * Hc + k];
        }
    } else {
        int q = idx - 245760;       // 4096
        int k = q >> 5, c = q & 31;
        in_wt[q] = in_w[c * Hc + k];
    }
}

// ------- input proj + layer-0 hi/hj: 2 rows per block, 256 threads -------
__global__ __launch_bounds__(256) void input_proj_hij(
    const float* __restrict__ nf, const float* __restrict__ in_wt,
    const float* __restrict__ in_b,
    const float* __restrict__ w1et0, const float* __restrict__ b1e0,
    const float* __restrict__ fold0,
    float* __restrict__ h, float* __restrict__ hi, float* __restrict__ hj) {
    int r0 = blockIdx.x * 2;
    int t = threadIdx.x;
    int k = t & 127, row = t >> 7;
    __shared__ float nfs[2][32];
    __shared__ float hs[2][Hc];
    if (t < 64) nfs[t >> 5][t & 31] = nf[r0 * 32 + t];
    __syncthreads();
    float acc = in_b[k];
    const float* wr = in_wt + k * 32;
#pragma unroll
    for (int c = 0; c < 32; c += 4) {
        float4 wv = *(const float4*)&wr[c];
        float4 av = *(const float4*)&nfs[row][c];
        acc += av.x * wv.x + av.y * wv.y + av.z * wv.z + av.w * wv.w;
    }
    h[(size_t)(r0 + row) * Hc + k] = acc;
    hs[row][k] = acc;
    __syncthreads();
    float a1 = b1e0[k] + fold0[k];   // b1 + contact fold
    float aj = 0.f;
    const float* we = w1et0 + k * 256;
#pragma unroll 8
    for (int c = 0; c < Hc; c += 4) {
        float4 w1v = *(const float4*)&we[c];
        float4 w2v = *(const float4*)&we[128 + c];
        float4 hv  = *(const float4*)&hs[row][c];
        a1 += hv.x * w1v.x + hv.y * w1v.y + hv.z * w1v.z + hv.w * w1v.w;
        aj += hv.x * w2v.x + hv.y * w2v.y + hv.z * w2v.z + hv.w * w2v.w;
    }
    hi[(size_t)(r0 + row) * Hc + k] = a1;
    hj[(size_t)(r0 + row) * Hc + k] = aj;
}

// ---------------- edge kernel: per (b,i) row, sparse edges, MFMA ----------------
// m_i = sum_{j in edges(i)} silu( silu(pre_ij) @ w2 + b2 )
// pre_ij = hi'[i] + hj[j] + dist(i,j)*w1d   (b1 + contact*w1c folded into hi')
// S (32 edges x 128 c) staged as bf16 in LDS, 16B-block XOR-swizzled by (row&7).
// B (w2t bf16, [col][k]) lives in 8 register fragments per wave for the whole kernel.
__global__ __launch_bounds__(256) void edge_kernel(
    const float* __restrict__ hi, const float* __restrict__ hj,
    const float* __restrict__ coords,
    const unsigned short* __restrict__ elist, const int* __restrict__ ecnt,
    const float* __restrict__ w1d, const __bf16* __restrict__ w2t,
    const float* __restrict__ b2, float* __restrict__ m_out) {
    int r = blockIdx.x;
    int b = r >> 9;
    int i = r & (Lc - 1);
    int t = threadIdx.x;
    int l = t & 63, w = t >> 6;          // lane, wave (wave w owns cols w*32..+31)

    __shared__ __bf16 S[32 * Hc];        // swizzled [edge][c]
    __shared__ float dL[Lc];
    __shared__ unsigned short jLs[Lc];

    int cnt = ecnt[r];

    float cx = coords[(b * Lc + i) * 3 + 0];
    float cy = coords[(b * Lc + i) * 3 + 1];
    float cz = coords[(b * Lc + i) * 3 + 2];
    for (int e = t; e < cnt; e += 256) {
        int j = elist[r * Lc + e];
        float dx = cx - coords[(b * Lc + j) * 3 + 0];
        float dy = cy - coords[(b * Lc + j) * 3 + 1];
        float dz = cz - coords[(b * Lc + j) * 3 + 2];
        dL[e] = sqrtf(dx * dx + dy * dy + dz * dz);
        jLs[e] = (unsigned short)j;
    }

    // fill-role constants: thread owns (edge e_f, 16-col slice c0)
    int e_f = t >> 3;                    // 0..31
    int cg  = t & 7;
    int c0  = cg * 16;
    float4 hi4[4], wd4[4];
#pragma unroll
    for (int q = 0; q < 4; q++) {
        hi4[q] = *(const float4*)&hi[(size_t)r * Hc + c0 + q * 4];
        wd4[q] = *(const float4*)&w1d[c0 + q * 4];
    }

    // B fragments: B[k][col], lane holds col=(l&15) of its N-tile, k-slice (l>>4)*8
    bf16x8 bf[2][4];
#pragma unroll
    for (int nt = 0; nt < 2; nt++)
#pragma unroll
        for (int kk = 0; kk < 4; kk++)
            bf[nt][kk] = *(const bf16x8*)&w2t[
                (size_t)(w * 32 + nt * 16 + (l & 15)) * Hc + kk * 32 + (l >> 4) * 8];

    float b2v[2] = { b2[w * 32 + (l & 15)], b2[w * 32 + 16 + (l & 15)] };
    float msum[2] = { 0.f, 0.f };

    __syncthreads();

    int row0 = l & 15, g = l >> 4, swz = l & 7;
    for (int base = 0; base < cnt; base += 32) {
        // ---- fill S (bf16, swizzled) ----
        bf16x8 o0, o1;
        if (base + e_f < cnt) {
            int j = jLs[base + e_f];
            float d = dL[base + e_f];
            const float* hjrow = hj + ((size_t)(b * Lc + j)) * Hc + c0;
            float v[16];
#pragma unroll
            for (int q = 0; q < 4; q++) {
                float4 hjv = *(const float4*)&hjrow[q * 4];
                v[q * 4 + 0] = silu(hi4[q].x + hjv.x + d * wd4[q].x);
                v[q * 4 + 1] = silu(hi4[q].y + hjv.y + d * wd4[q].y);
                v[q * 4 + 2] = silu(hi4[q].z + hjv.z + d * wd4[q].z);
                v[q * 4 + 3] = silu(hi4[q].w + hjv.w + d * wd4[q].w);
            }
#pragma unroll
            for (int u = 0; u < 8; u++) {
                o0[u] = (__bf16)v[u];
                o1[u] = (__bf16)v[8 + u];
            }
        } else {
#pragma unroll
            for (int u = 0; u < 8; u++) { o0[u] = (__bf16)0.f; o1[u] = (__bf16)0.f; }
        }
        int sw = e_f & 7;
        *(bf16x8*)&S[e_f * Hc + ((cg * 2) ^ sw) * 8]     = o0;
        *(bf16x8*)&S[e_f * Hc + ((cg * 2 + 1) ^ sw) * 8] = o1;
        __syncthreads();

        // ---- MFMA: D[edge][col] = S @ w2 ----
        f32x4 acc[2][2] = {};
#pragma unroll
        for (int kk = 0; kk < 4; kk++) {
            bf16x8 a0 = *(const bf16x8*)&S[row0 * Hc + (((kk * 4 + g) ^ swz)) * 8];
            bf16x8 a1 = *(const bf16x8*)&S[(16 + row0) * Hc + (((kk * 4 + g) ^ swz)) * 8];
            acc[0][0] = __builtin_amdgcn_mfma_f32_16x16x32_bf16(a0, bf[0][kk], acc[0][0], 0, 0, 0);
            acc[0][1] = __builtin_amdgcn_mfma_f32_16x16x32_bf16(a0, bf[1][kk], acc[0][1], 0, 0, 0);
            acc[1][0] = __builtin_amdgcn_mfma_f32_16x16x32_bf16(a1, bf[0][kk], acc[1][0], 0, 0, 0);
            acc[1][1] = __builtin_amdgcn_mfma_f32_16x16x32_bf16(a1, bf[1][kk], acc[1][1], 0, 0, 0);
        }

        // ---- second silu + predicated colsum into registers ----
#pragma unroll
        for (int mt = 0; mt < 2; mt++)
#pragma unroll
            for (int nt = 0; nt < 2; nt++)
#pragma unroll
                for (int jj = 0; jj < 4; jj++) {
                    int er = mt * 16 + g * 4 + jj;   // D row = 4*(lane>>4)+reg (+16*mt)
                    if (base + er < cnt)
                        msum[nt] += silu(acc[mt][nt][jj] + b2v[nt]);
                }
        __syncthreads();   // protect S before next fill
    }

    // cross-lane colsum: lanes l, l^16, l^32 share col (l&15)
    float v0 = msum[0]; v0 += __shfl_xor(v0, 16); v0 += __shfl_xor(v0, 32);
    float v1 = msum[1]; v1 += __shfl_xor(v1, 16); v1 += __shfl_xor(v1, 32);
    if (l < 16) {
        m_out[(size_t)r * Hc + w * 32 + l]      = v0;
        m_out[(size_t)r * Hc + w * 32 + 16 + l] = v1;
    }
}

// ------- node update (+ next layer hi/hj): 2 rows per block, 256 threads -------
// h' = h + silu([h||m] @ w1n + b1n) @ w2n + b2n     (w1nt/w2nt transposed [k][c])
// if do_hij: hi = h'@w1e[:H] + b1e + fold;  hj = h'@w1e[H:2H]   (w1et [k][hi||hj])
__global__ __launch_bounds__(256) void node_hij_kernel(
    const float* __restrict__ h, const float* __restrict__ m,
    const float* __restrict__ w1nt, const float* __restrict__ b1n,
    const float* __restrict__ w2nt, const float* __restrict__ b2n,
    float* __restrict__ hout, int do_hij,
    const float* __restrict__ w1et, const float* __restrict__ b1e,
    const float* __restrict__ fold,
    float* __restrict__ hi, float* __restrict__ hj) {
    int r0 = blockIdx.x * 2;
    int t = threadIdx.x;
    int k = t & 127, row = t >> 7;
    __shared__ float act[2][256];     // [row][ h(0:128) || m(128:256) ]
    __shared__ float ss[2][Hc];
    __shared__ float hn[2][Hc];
    act[row][k]       = h[(size_t)(r0 + row) * Hc + k];
    act[row][128 + k] = m[(size_t)(r0 + row) * Hc + k];
    __syncthreads();
    // phase 1: npre
    float acc = b1n[k];
    const float* wr = w1nt + k * 256;
#pragma unroll 8
    for (int c = 0; c < 256; c += 4) {
        float4 wv = *(const float4*)&wr[c];
        float4 av = *(const float4*)&act[row][c];
        acc += av.x * wv.x + av.y * wv.y + av.z * wv.z + av.w * wv.w;
    }
    ss[row][k] = silu(acc);
    __syncthreads();
    // phase 2: delta + residual
    float a2 = b2n[k];
    const float* w2r = w2nt + k * Hc;
#pragma unroll 8
    for (int c = 0; c < Hc; c += 4) {
        float4 wv = *(const float4*)&w2r[c];
        float4 sv = *(const float4*)&ss[row][c];
        a2 += sv.x * wv.x + sv.y * wv.y + sv.z * wv.z + sv.w * wv.w;
    }
    float hnew = act[row][k] + a2;
    hout[(size_t)(r0 + row) * Hc + k] = hnew;
    if (do_hij) {
        hn[row][k] = hnew;
        __syncthreads();
        float a1 = b1e[k] + fold[k];
        float aj = 0.f;
        const float* we = w1et + k * 256;
#pragma unroll 8
        for (int c = 0; c < Hc; c += 4) {
            float4 w1v = *(const float4*)&we[c];
            float4 w2v = *(const float4*)&we[128 + c];
            float4 hv  = *(const float4*)&hn[row][c];
            a1 += hv.x * w1v.x + hv.y * w1v.y + hv.z * w1v.z + hv.w * w1v.w;
            aj += hv.x * w2v.x + hv.y * w2v.y + hv.z * w2v.z + hv.w * w2v.w;
        }
        hi[(size_t)(r0 + row) * Hc + k] = a1;
        hj[(size_t)(r0 + row) * Hc + k] = aj;
    }
}

extern "C" void kernel_launch(void* const* d_in, const int* in_sizes, int n_in,
                              void* d_out, int out_size, void* d_ws, size_t ws_size,
                              hipStream_t stream) {
    const float* coords     = (const float*)d_in[0];
    const float* contacts   = (const float*)d_in[1];
    const float* node_feats = (const float*)d_in[2];
    const float* in_w       = (const float*)d_in[3];
    const float* in_b       = (const float*)d_in[4];
    const float* e_w1       = (const float*)d_in[5];   // 3 x 258 x 128
    const float* e_b1       = (const float*)d_in[6];
    const float* e_w2       = (const float*)d_in[7];   // 3 x 128 x 128
    const float* e_b2       = (const float*)d_in[8];
    const float* n_w1       = (const float*)d_in[9];   // 3 x 256 x 128
    const float* n_b1       = (const float*)d_in[10];
    const float* n_w2       = (const float*)d_in[11];  // 3 x 128 x 128
    const float* n_b2       = (const float*)d_in[12];

    float* ws = (float*)d_ws;
    float* h  = ws;                                    // 131072 floats
    float* hi = ws + 131072;
    float* hj = ws + 262144;
    float* m  = ws + 393216;
    unsigned short* elist = (unsigned short*)(ws + 524288);   // 1 MiB = 262144 floats
    int*   ecnt = (int*)(ws + 786432);                        // 1024 ints
    __bf16* w2t = (__bf16*)(ws + 787456);                     // 24576 floats
    float* w1nt = ws + 812032;                                // 3*128*256 = 98304
    float* w2nt = ws + 910336;                                // 3*128*128 = 49152
    float* w1et = ws + 959488;                                // 3*128*256 = 98304
    float* in_wt = ws + 1057792;                              // 128*32 = 4096

    prep_node_t<<<976, 256, 0, stream>>>(n_w1, n_w2, e_w1, in_w,
                                         w1nt, w2nt, w1et, in_wt);
    prep_w2t<<<3 * Hc, 128, 0, stream>>>(e_w2, w2t);
    build_edges<<<ROWS, 64, 0, stream>>>(contacts, elist, ecnt);
    input_proj_hij<<<ROWS / 2, 256, 0, stream>>>(
        node_feats, in_wt, in_b,
        w1et, e_b1, e_w1 + (size_t)257 * Hc,   // layer-0 transposed w1e + fold row
        h, hi, hj);

    for (int l = 0; l < 3; l++) {
        const float* w1  = e_w1 + (size_t)l * 258 * Hc;
        edge_kernel<<<ROWS, 256, 0, stream>>>(hi, hj, coords, elist, ecnt,
                                              w1 + 2 * Hc * Hc,
                                              w2t + (size_t)l * Hc * Hc,
                                              e_b2 + l * Hc, m);
        int do_hij = (l < 2);
        int lnext = (l + 1 < 3) ? l + 1 : 0;
        float* hout = (l == 2) ? (float*)d_out : h;
        node_hij_kernel<<<ROWS / 2, 256, 0, stream>>>(
            h, m,
            w1nt + (size_t)l * 128 * 256, n_b1 + l * Hc,
            w2nt + (size_t)l * 128 * 128, n_b2 + l * Hc,
            hout, do_hij,
            w1et + (size_t)lnext * 128 * 256, e_b1 + lnext * Hc,
            e_w1 + (size_t)lnext * 258 * Hc + (size_t)257 * Hc,
            hi, hj);
    }
}

// Round 7
// 167.924 us; speedup vs baseline: 1.5020x; 1.5020x over previous
//
#include <hip/hip_runtime.h>
#include <hip/hip_bf16.h>

// SE3StructEncoder: sparse edge-MLP graph network. B=2, L=512, H=128, 3 layers.
// Round 7: node/input path -> bf16 MFMA GEMMs (same fragment convention as the
// validated edge kernel). Node was L2-latency-bound at 39us with VALUBusy 7%;
// scalar matvec replaced by 16-row-tile MFMA (64 blocks). Edge kernel unchanged.

#define Hc 128
#define Lc 512
#define ROWS 1024     // B*L

typedef __bf16 bf16x8 __attribute__((ext_vector_type(8)));
typedef float  f32x4  __attribute__((ext_vector_type(4)));

__device__ __forceinline__ float silu(float x) {
    return x / (1.f + __expf(-x));
}

// ---------------- edge-list build: one wave per (b,i) row ----------------
__global__ __launch_bounds__(64) void build_edges(
    const float* __restrict__ contacts,
    unsigned short* __restrict__ elist, int* __restrict__ ecnt) {
    int r = blockIdx.x;
    int lane = threadIdx.x;
    const float* row = contacts + (size_t)r * Lc;
    int cnt = 0;
    for (int base = 0; base < Lc; base += 64) {
        float v = row[base + lane];
        unsigned long long mask = __ballot(v > 0.f);
        if (v > 0.f) {
            int pos = cnt + __popcll(mask & ((1ull << lane) - 1ull));
            elist[r * Lc + pos] = (unsigned short)(base + lane);
        }
        cnt += __popcll(mask);
    }
    if (lane == 0) ecnt[r] = cnt;
}

// ---- ALL weights -> bf16 transposed [col][k] (one-time per launch) ----
// in_wt[col][k]  (128x32)   = in_w[k][col]
// w1et[l][col][k] (256x128) = col<128 ? e_w1[l][k][col] : e_w1[l][128+k][col-128]
// w2te[l][col][k] (128x128) = e_w2[l][k][col]
// w1nt[l][col][k] (128x256) = n_w1[l][k][col]
// w2nt[l][col][k] (128x128) = n_w2[l][k][col]
__global__ __launch_bounds__(256) void prep_wbf(
    const float* __restrict__ in_w, const float* __restrict__ e_w1,
    const float* __restrict__ e_w2, const float* __restrict__ n_w1,
    const float* __restrict__ n_w2,
    __bf16* __restrict__ in_wt, __bf16* __restrict__ w1et,
    __bf16* __restrict__ w2te, __bf16* __restrict__ w1nt,
    __bf16* __restrict__ w2nt) {
    int idx = blockIdx.x * 256 + threadIdx.x;   // 1168*256 = 299008 exactly
    if (idx < 4096) {
        int col = idx >> 5, k = idx & 31;
        in_wt[idx] = (__bf16)in_w[k * Hc + col];
    } else if (idx < 4096 + 98304) {
        int q = idx - 4096;
        int l = q / 32768, r = q % 32768;
        int col = r >> 7, k = r & 127;
        float v = (col < 128) ? e_w1[(size_t)l * 258 * Hc + k * Hc + col]
                              : e_w1[(size_t)l * 258 * Hc + (128 + k) * Hc + (col - 128)];
        w1et[q] = (__bf16)v;
    } else if (idx < 4096 + 98304 + 49152) {
        int q = idx - 4096 - 98304;
        int l = q / 16384, r = q % 16384;
        int col = r >> 7, k = r & 127;
        w2te[q] = (__bf16)e_w2[(size_t)l * 16384 + k * Hc + col];
    } else if (idx < 4096 + 98304 + 49152 + 98304) {
        int q = idx - 4096 - 98304 - 49152;
        int l = q / 32768, r = q % 32768;
        int col = r >> 8, k = r & 255;
        w1nt[q] = (__bf16)n_w1[(size_t)l * 32768 + k * Hc + col];
    } else {
        int q = idx - 4096 - 98304 - 49152 - 98304;
        int l = q / 16384, r = q % 16384;
        int col = r >> 7, k = r & 127;
        w2nt[q] = (__bf16)n_w2[(size_t)l * 16384 + k * Hc + col];
    }
}

// ------- input proj + layer-0 hi/hj via MFMA: 16 rows/block, 64 blocks -------
__global__ __launch_bounds__(256) void input_mfma(
    const float* __restrict__ nf, const __bf16* __restrict__ in_wt,
    const float* __restrict__ in_b,
    const __bf16* __restrict__ w1et0, const float* __restrict__ b1e,
    const float* __restrict__ fold,
    float* __restrict__ h, float* __restrict__ hi, float* __restrict__ hj) {
    int r0 = blockIdx.x * 16;
    int t = threadIdx.x;
    int l = t & 63, w = t >> 6;
    int lr = l & 15, g = l >> 4;
    __shared__ __bf16 A0[16 * 32];     // swizzled [row][k], blk ^ (row&3)
    __shared__ __bf16 A3[16 * Hc];     // swizzled [row][k], blk ^ (row&7)

    if (t < 64) {
        int row = t >> 2, blk = t & 3, k0 = blk * 8;
        const float* src = &nf[(size_t)(r0 + row) * 32 + k0];
        float4 v0 = *(const float4*)src, v1 = *(const float4*)(src + 4);
        bf16x8 o;
        o[0] = (__bf16)v0.x; o[1] = (__bf16)v0.y; o[2] = (__bf16)v0.z; o[3] = (__bf16)v0.w;
        o[4] = (__bf16)v1.x; o[5] = (__bf16)v1.y; o[6] = (__bf16)v1.z; o[7] = (__bf16)v1.w;
        *(bf16x8*)&A0[row * 32 + (blk ^ (row & 3)) * 8] = o;
    }
    // B frags: h-proj (K=32, 1 step)
    int c0 = w * 32;
    bf16x8 bf0[2];
#pragma unroll
    for (int nt = 0; nt < 2; nt++)
        bf0[nt] = *(const bf16x8*)&in_wt[(size_t)(c0 + nt * 16 + lr) * 32 + g * 8];
    __syncthreads();
    f32x4 acc[2] = {};
    {
        bf16x8 a = *(const bf16x8*)&A0[lr * 32 + (g ^ (lr & 3)) * 8];
        acc[0] = __builtin_amdgcn_mfma_f32_16x16x32_bf16(a, bf0[0], acc[0], 0, 0, 0);
        acc[1] = __builtin_amdgcn_mfma_f32_16x16x32_bf16(a, bf0[1], acc[1], 0, 0, 0);
    }
#pragma unroll
    for (int nt = 0; nt < 2; nt++) {
        int col = c0 + nt * 16 + lr;
        float bb = in_b[col];
#pragma unroll
        for (int j = 0; j < 4; j++) {
            int row = g * 4 + j;
            float hv = acc[nt][j] + bb;
            h[(size_t)(r0 + row) * Hc + col] = hv;
            A3[row * Hc + ((col >> 3) ^ (row & 7)) * 8 + (col & 7)] = (__bf16)hv;
        }
    }
    __syncthreads();
    // hi/hj: [16x128] @ w1et0 [256 cols x 128 k]
    int c3 = w * 64;
    bf16x8 b3[4][4];
#pragma unroll
    for (int nt = 0; nt < 4; nt++)
#pragma unroll
        for (int ks = 0; ks < 4; ks++)
            b3[nt][ks] = *(const bf16x8*)&w1et0[
                (size_t)(c3 + nt * 16 + lr) * Hc + ks * 32 + g * 8];
    f32x4 acc3[4] = {};
#pragma unroll
    for (int ks = 0; ks < 4; ks++) {
        bf16x8 a = *(const bf16x8*)&A3[lr * Hc + (((ks * 4 + g) ^ (lr & 7))) * 8];
#pragma unroll
        for (int nt = 0; nt < 4; nt++)
            acc3[nt] = __builtin_amdgcn_mfma_f32_16x16x32_bf16(a, b3[nt][ks], acc3[nt], 0, 0, 0);
    }
#pragma unroll
    for (int nt = 0; nt < 4; nt++) {
        int col = c3 + nt * 16 + lr;
#pragma unroll
        for (int j = 0; j < 4; j++) {
            int row = g * 4 + j;
            if (col < 128)
                hi[(size_t)(r0 + row) * Hc + col] = acc3[nt][j] + b1e[col] + fold[col];
            else
                hj[(size_t)(r0 + row) * Hc + (col - 128)] = acc3[nt][j];
        }
    }
}

// ---------------- edge kernel: per (b,i) row, sparse edges, MFMA ----------------
// (unchanged from round 5 -- validated)
__global__ __launch_bounds__(256) void edge_kernel(
    const float* __restrict__ hi, const float* __restrict__ hj,
    const float* __restrict__ coords,
    const unsigned short* __restrict__ elist, const int* __restrict__ ecnt,
    const float* __restrict__ w1d, const __bf16* __restrict__ w2t,
    const float* __restrict__ b2, float* __restrict__ m_out) {
    int r = blockIdx.x;
    int b = r >> 9;
    int i = r & (Lc - 1);
    int t = threadIdx.x;
    int l = t & 63, w = t >> 6;

    __shared__ __bf16 S[32 * Hc];
    __shared__ float dL[Lc];
    __shared__ unsigned short jLs[Lc];

    int cnt = ecnt[r];

    float cx = coords[(b * Lc + i) * 3 + 0];
    float cy = coords[(b * Lc + i) * 3 + 1];
    float cz = coords[(b * Lc + i) * 3 + 2];
    for (int e = t; e < cnt; e += 256) {
        int j = elist[r * Lc + e];
        float dx = cx - coords[(b * Lc + j) * 3 + 0];
        float dy = cy - coords[(b * Lc + j) * 3 + 1];
        float dz = cz - coords[(b * Lc + j) * 3 + 2];
        dL[e] = sqrtf(dx * dx + dy * dy + dz * dz);
        jLs[e] = (unsigned short)j;
    }

    int e_f = t >> 3;
    int cg  = t & 7;
    int c0  = cg * 16;
    float4 hi4[4], wd4[4];
#pragma unroll
    for (int q = 0; q < 4; q++) {
        hi4[q] = *(const float4*)&hi[(size_t)r * Hc + c0 + q * 4];
        wd4[q] = *(const float4*)&w1d[c0 + q * 4];
    }

    bf16x8 bf[2][4];
#pragma unroll
    for (int nt = 0; nt < 2; nt++)
#pragma unroll
        for (int kk = 0; kk < 4; kk++)
            bf[nt][kk] = *(const bf16x8*)&w2t[
                (size_t)(w * 32 + nt * 16 + (l & 15)) * Hc + kk * 32 + (l >> 4) * 8];

    float b2v[2] = { b2[w * 32 + (l & 15)], b2[w * 32 + 16 + (l & 15)] };
    float msum[2] = { 0.f, 0.f };

    __syncthreads();

    int row0 = l & 15, g = l >> 4, swz = l & 7;
    for (int base = 0; base < cnt; base += 32) {
        bf16x8 o0, o1;
        if (base + e_f < cnt) {
            int j = jLs[base + e_f];
            float d = dL[base + e_f];
            const float* hjrow = hj + ((size_t)(b * Lc + j)) * Hc + c0;
            float v[16];
#pragma unroll
            for (int q = 0; q < 4; q++) {
                float4 hjv = *(const float4*)&hjrow[q * 4];
                v[q * 4 + 0] = silu(hi4[q].x + hjv.x + d * wd4[q].x);
                v[q * 4 + 1] = silu(hi4[q].y + hjv.y + d * wd4[q].y);
                v[q * 4 + 2] = silu(hi4[q].z + hjv.z + d * wd4[q].z);
                v[q * 4 + 3] = silu(hi4[q].w + hjv.w + d * wd4[q].w);
            }
#pragma unroll
            for (int u = 0; u < 8; u++) {
                o0[u] = (__bf16)v[u];
                o1[u] = (__bf16)v[8 + u];
            }
        } else {
#pragma unroll
            for (int u = 0; u < 8; u++) { o0[u] = (__bf16)0.f; o1[u] = (__bf16)0.f; }
        }
        int sw = e_f & 7;
        *(bf16x8*)&S[e_f * Hc + ((cg * 2) ^ sw) * 8]     = o0;
        *(bf16x8*)&S[e_f * Hc + ((cg * 2 + 1) ^ sw) * 8] = o1;
        __syncthreads();

        f32x4 acc[2][2] = {};
#pragma unroll
        for (int kk = 0; kk < 4; kk++) {
            bf16x8 a0 = *(const bf16x8*)&S[row0 * Hc + (((kk * 4 + g) ^ swz)) * 8];
            bf16x8 a1 = *(const bf16x8*)&S[(16 + row0) * Hc + (((kk * 4 + g) ^ swz)) * 8];
            acc[0][0] = __builtin_amdgcn_mfma_f32_16x16x32_bf16(a0, bf[0][kk], acc[0][0], 0, 0, 0);
            acc[0][1] = __builtin_amdgcn_mfma_f32_16x16x32_bf16(a0, bf[1][kk], acc[0][1], 0, 0, 0);
            acc[1][0] = __builtin_amdgcn_mfma_f32_16x16x32_bf16(a1, bf[0][kk], acc[1][0], 0, 0, 0);
            acc[1][1] = __builtin_amdgcn_mfma_f32_16x16x32_bf16(a1, bf[1][kk], acc[1][1], 0, 0, 0);
        }

#pragma unroll
        for (int mt = 0; mt < 2; mt++)
#pragma unroll
            for (int nt = 0; nt < 2; nt++)
#pragma unroll
                for (int jj = 0; jj < 4; jj++) {
                    int er = mt * 16 + g * 4 + jj;
                    if (base + er < cnt)
                        msum[nt] += silu(acc[mt][nt][jj] + b2v[nt]);
                }
        __syncthreads();
    }

    float v0 = msum[0]; v0 += __shfl_xor(v0, 16); v0 += __shfl_xor(v0, 32);
    float v1 = msum[1]; v1 += __shfl_xor(v1, 16); v1 += __shfl_xor(v1, 32);
    if (l < 16) {
        m_out[(size_t)r * Hc + w * 32 + l]      = v0;
        m_out[(size_t)r * Hc + w * 32 + 16 + l] = v1;
    }
}

// ------- node update + next-layer hi/hj via MFMA: 16 rows/block, 64 blocks -------
// h' = h + silu([h||m]@w1n + b1n)@w2n + b2n ; hi/hj = h'@w1e (+b1e+fold)
__global__ __launch_bounds__(256) void node_mfma(
    const float* __restrict__ h, const float* __restrict__ m,
    const __bf16* __restrict__ w1nt, const float* __restrict__ b1n,
    const __bf16* __restrict__ w2nt, const float* __restrict__ b2n,
    float* __restrict__ hout, int do_hij,
    const __bf16* __restrict__ w1et, const float* __restrict__ b1e,
    const float* __restrict__ fold,
    float* __restrict__ hi, float* __restrict__ hj) {
    int r0 = blockIdx.x * 16;
    int t = threadIdx.x;
    int l = t & 63, w = t >> 6;
    int lr = l & 15, g = l >> 4;
    __shared__ __bf16 A1[16 * 256];   // [row][k] swizzled (32 blks/row, blk^(row&7))
    __shared__ __bf16 A2[16 * Hc];    // silu(npre)
    __shared__ __bf16 A3[16 * Hc];    // h'
    __shared__ float hbuf[16 * Hc];

    // stage [h||m] -> A1 (bf16) and h -> hbuf (fp32)
#pragma unroll
    for (int it = 0; it < 2; it++) {
        int idx = t + it * 256;       // 0..511 16B blocks
        int row = idx >> 5, blk = idx & 31, k0 = blk * 8;
        const float* src = (k0 < 128)
            ? &h[(size_t)(r0 + row) * Hc + k0]
            : &m[(size_t)(r0 + row) * Hc + (k0 - 128)];
        float4 v0 = *(const float4*)src, v1 = *(const float4*)(src + 4);
        bf16x8 o;
        o[0] = (__bf16)v0.x; o[1] = (__bf16)v0.y; o[2] = (__bf16)v0.z; o[3] = (__bf16)v0.w;
        o[4] = (__bf16)v1.x; o[5] = (__bf16)v1.y; o[6] = (__bf16)v1.z; o[7] = (__bf16)v1.w;
        *(bf16x8*)&A1[row * 256 + (blk ^ (row & 7)) * 8] = o;
        if (k0 < 128) {
            *(float4*)&hbuf[row * Hc + k0] = v0;
            *(float4*)&hbuf[row * Hc + k0 + 4] = v1;
        }
    }
    // phase-1 B frags (K=256)
    int c0 = w * 32;
    bf16x8 b1f[2][8];
#pragma unroll
    for (int nt = 0; nt < 2; nt++)
#pragma unroll
        for (int ks = 0; ks < 8; ks++)
            b1f[nt][ks] = *(const bf16x8*)&w1nt[
                (size_t)(c0 + nt * 16 + lr) * 256 + ks * 32 + g * 8];
    __syncthreads();

    f32x4 acc[2] = {};
#pragma unroll
    for (int ks = 0; ks < 8; ks++) {
        bf16x8 a = *(const bf16x8*)&A1[lr * 256 + (((ks * 4 + g) ^ (lr & 7))) * 8];
        acc[0] = __builtin_amdgcn_mfma_f32_16x16x32_bf16(a, b1f[0][ks], acc[0], 0, 0, 0);
        acc[1] = __builtin_amdgcn_mfma_f32_16x16x32_bf16(a, b1f[1][ks], acc[1], 0, 0, 0);
    }
#pragma unroll
    for (int nt = 0; nt < 2; nt++) {
        int col = c0 + nt * 16 + lr;
        float bb = b1n[col];
#pragma unroll
        for (int j = 0; j < 4; j++) {
            int row = g * 4 + j;
            A2[row * Hc + ((col >> 3) ^ (row & 7)) * 8 + (col & 7)] =
                (__bf16)silu(acc[nt][j] + bb);
        }
    }
    __syncthreads();

    // phase 2: delta = A2 @ w2n ; h' = h + delta + b2n
    bf16x8 b2f[2][4];
#pragma unroll
    for (int nt = 0; nt < 2; nt++)
#pragma unroll
        for (int ks = 0; ks < 4; ks++)
            b2f[nt][ks] = *(const bf16x8*)&w2nt[
                (size_t)(c0 + nt * 16 + lr) * Hc + ks * 32 + g * 8];
    f32x4 acc2[2] = {};
#pragma unroll
    for (int ks = 0; ks < 4; ks++) {
        bf16x8 a = *(const bf16x8*)&A2[lr * Hc + (((ks * 4 + g) ^ (lr & 7))) * 8];
        acc2[0] = __builtin_amdgcn_mfma_f32_16x16x32_bf16(a, b2f[0][ks], acc2[0], 0, 0, 0);
        acc2[1] = __builtin_amdgcn_mfma_f32_16x16x32_bf16(a, b2f[1][ks], acc2[1], 0, 0, 0);
    }
#pragma unroll
    for (int nt = 0; nt < 2; nt++) {
        int col = c0 + nt * 16 + lr;
        float bb = b2n[col];
#pragma unroll
        for (int j = 0; j < 4; j++) {
            int row = g * 4 + j;
            float hnew = hbuf[row * Hc + col] + acc2[nt][j] + bb;
            hout[(size_t)(r0 + row) * Hc + col] = hnew;
            A3[row * Hc + ((col >> 3) ^ (row & 7)) * 8 + (col & 7)] = (__bf16)hnew;
        }
    }
    if (!do_hij) return;
    __syncthreads();

    // phase 3: hi/hj = A3 @ w1et (256 output cols)
    int c3 = w * 64;
    bf16x8 b3[4][4];
#pragma unroll
    for (int nt = 0; nt < 4; nt++)
#pragma unroll
        for (int ks = 0; ks < 4; ks++)
            b3[nt][ks] = *(const bf16x8*)&w1et[
                (size_t)(c3 + nt * 16 + lr) * Hc + ks * 32 + g * 8];
    f32x4 acc3[4] = {};
#pragma unroll
    for (int ks = 0; ks < 4; ks++) {
        bf16x8 a = *(const bf16x8*)&A3[lr * Hc + (((ks * 4 + g) ^ (lr & 7))) * 8];
#pragma unroll
        for (int nt = 0; nt < 4; nt++)
            acc3[nt] = __builtin_amdgcn_mfma_f32_16x16x32_bf16(a, b3[nt][ks], acc3[nt], 0, 0, 0);
    }
#pragma unroll
    for (int nt = 0; nt < 4; nt++) {
        int col = c3 + nt * 16 + lr;
#pragma unroll
        for (int j = 0; j < 4; j++) {
            int row = g * 4 + j;
            if (col < 128)
                hi[(size_t)(r0 + row) * Hc + col] = acc3[nt][j] + b1e[col] + fold[col];
            else
                hj[(size_t)(r0 + row) * Hc + (col - 128)] = acc3[nt][j];
        }
    }
}

extern "C" void kernel_launch(void* const* d_in, const int* in_sizes, int n_in,
                              void* d_out, int out_size, void* d_ws, size_t ws_size,
                              hipStream_t stream) {
    const float* coords     = (const float*)d_in[0];
    const float* contacts   = (const float*)d_in[1];
    const float* node_feats = (const float*)d_in[2];
    const float* in_w       = (const float*)d_in[3];
    const float* in_b       = (const float*)d_in[4];
    const float* e_w1       = (const float*)d_in[5];   // 3 x 258 x 128
    const float* e_b1       = (const float*)d_in[6];
    const float* e_w2       = (const float*)d_in[7];   // 3 x 128 x 128
    const float* e_b2       = (const float*)d_in[8];
    const float* n_w1       = (const float*)d_in[9];   // 3 x 256 x 128
    const float* n_b1       = (const float*)d_in[10];
    const float* n_w2       = (const float*)d_in[11];  // 3 x 128 x 128
    const float* n_b2       = (const float*)d_in[12];

    float* ws = (float*)d_ws;
    float* h  = ws;                                    // 131072 floats
    float* hi = ws + 131072;
    float* hj = ws + 262144;
    float* m  = ws + 393216;
    unsigned short* elist = (unsigned short*)(ws + 524288);   // 262144 floats
    int*   ecnt = (int*)(ws + 786432);                        // 1024
    __bf16* in_wt = (__bf16*)(ws + 787456);                   // 4096 bf16  = 2048 f
    __bf16* w1et  = (__bf16*)(ws + 789504);                   // 98304 bf16 = 49152 f
    __bf16* w2te  = (__bf16*)(ws + 838656);                   // 49152 bf16 = 24576 f
    __bf16* w1nt  = (__bf16*)(ws + 863232);                   // 98304 bf16 = 49152 f
    __bf16* w2nt  = (__bf16*)(ws + 912384);                   // 49152 bf16 = 24576 f

    prep_wbf<<<1168, 256, 0, stream>>>(in_w, e_w1, e_w2, n_w1, n_w2,
                                       in_wt, w1et, w2te, w1nt, w2nt);
    build_edges<<<ROWS, 64, 0, stream>>>(contacts, elist, ecnt);
    input_mfma<<<ROWS / 16, 256, 0, stream>>>(
        node_feats, in_wt, in_b,
        w1et, e_b1, e_w1 + (size_t)257 * Hc,
        h, hi, hj);

    for (int l = 0; l < 3; l++) {
        const float* w1 = e_w1 + (size_t)l * 258 * Hc;
        edge_kernel<<<ROWS, 256, 0, stream>>>(hi, hj, coords, elist, ecnt,
                                              w1 + 2 * Hc * Hc,
                                              w2te + (size_t)l * Hc * Hc,
                                              e_b2 + l * Hc, m);
        int do_hij = (l < 2);
        int lnext = (l + 1 < 3) ? l + 1 : 0;
        float* hout = (l == 2) ? (float*)d_out : h;
        node_mfma<<<ROWS / 16, 256, 0, stream>>>(
            h, m,
            w1nt + (size_t)l * 128 * 256, n_b1 + l * Hc,
            w2nt + (size_t)l * 128 * 128, n_b2 + l * Hc,
            hout, do_hij,
            w1et + (size_t)lnext * 256 * 128, e_b1 + lnext * Hc,
            e_w1 + (size_t)lnext * 258 * Hc + (size_t)257 * Hc,
            hi, hj);
    }
}